// Round 9
// baseline (446.826 us; speedup 1.0000x reference)
//
#include <hip/hip_runtime.h>
#include <hip/hip_bf16.h>

typedef __attribute__((ext_vector_type(8))) short short8;
typedef __attribute__((ext_vector_type(4))) float f32x4;
typedef __attribute__((ext_vector_type(2))) float f32x2;
typedef unsigned short u16;
typedef unsigned int u32;
typedef unsigned char u8;

#define NORM_INV (1.0f / 100.0f)

__device__ __forceinline__ float silu(float x) {
    return x * __builtin_amdgcn_rcpf(1.0f + __expf(-x));
}

__device__ __forceinline__ u16 f2bf(float x) {
    union { float f; u32 u; } v; v.f = x;
    u32 r = v.u + 0x7fff + ((v.u >> 16) & 1);   // RNE
    return (u16)(r >> 16);
}

// ---------------- kernel 0: weight transposes (tiny) ----------------
__global__ void prep_weights(const float* __restrict__ W1, const float* __restrict__ W2,
                             u16* __restrict__ W1abT, u16* __restrict__ W2T) {
    int idx = blockIdx.x * blockDim.x + threadIdx.x;
    if (idx < 256 * 128) {
        int j = idx >> 7, k = idx & 127;
        float v = (j < 128) ? W1[k * 128 + j] : W1[(128 + k) * 128 + (j - 128)];
        W1abT[j * 128 + k] = f2bf(v);
    } else if (idx < 256 * 128 + 128 * 128) {
        int t = idx - 256 * 128;
        int n = t >> 7, k = t & 127;
        W2T[n * 128 + k] = f2bf(W2[k * 128 + n]);
    }
}

// ---------------- kernel 1: AB8[node][256] = fp8[h@W1a + b1 | h@W1b] ----------------
__global__ __launch_bounds__(256) void ab_kernel(const float* __restrict__ h,
        const float* __restrict__ b1, const u16* __restrict__ W1abT,
        u8* __restrict__ AB8, int N) {
    __shared__ u16 hs[32 * 128];     // 32 nodes x 128 k, bf16, XOR-swizzled
    int tid = threadIdx.x;
    int n0 = blockIdx.x * 32;
    int lane = tid & 63, wave = tid >> 6;

    #pragma unroll
    for (int it = 0; it < 8; ++it) {
        int item = it * 256 + tid;          // 2048 items, 2 k each
        int m = item >> 6;
        int k = (item & 63) * 2;
        float2 hv = make_float2(0.f, 0.f);
        if (n0 + m < N) hv = *(const float2*)(h + (size_t)(n0 + m) * 128 + k);
        u32 pk = (u32)f2bf(hv.x) | ((u32)f2bf(hv.y) << 16);
        int byteoff = m * 256 + ((k * 2) ^ ((m & 7) << 4));
        *(u32*)((char*)hs + byteoff) = pk;
    }

    short8 bw[4][4];
    #pragma unroll
    for (int nt = 0; nt < 4; ++nt) {
        int j = wave * 64 + nt * 16 + (lane & 15);
        #pragma unroll
        for (int ks = 0; ks < 4; ++ks)
            bw[nt][ks] = *(const short8*)((const char*)W1abT + j * 256 + ks * 64 + (lane >> 4) * 16);
    }
    __syncthreads();

    f32x4 acc[2][4] = {};
    #pragma unroll
    for (int ks = 0; ks < 4; ++ks) {
        short8 a[2];
        #pragma unroll
        for (int mt = 0; mt < 2; ++mt) {
            int row = mt * 16 + (lane & 15);
            int byteoff = row * 256 + (((ks * 64) + ((lane >> 4) * 16)) ^ ((row & 7) << 4));
            a[mt] = *(short8*)((char*)hs + byteoff);
        }
        #pragma unroll
        for (int mt = 0; mt < 2; ++mt)
            #pragma unroll
            for (int nt = 0; nt < 4; ++nt)
                acc[mt][nt] = __builtin_amdgcn_mfma_f32_16x16x32_bf16(a[mt], bw[nt][ks], acc[mt][nt], 0, 0, 0);
    }

    // epilogue: + b1 on A-half, store fp8 e4m3 (byte per element)
    #pragma unroll
    for (int mt = 0; mt < 2; ++mt) {
        #pragma unroll
        for (int nt = 0; nt < 4; ++nt) {
            int j = wave * 64 + nt * 16 + (lane & 15);
            float bias = (j < 128) ? b1[j] : 0.f;
            #pragma unroll
            for (int r = 0; r < 4; ++r) {
                int node = n0 + mt * 16 + (lane >> 4) * 4 + r;
                if (node < N) {
                    float v = acc[mt][nt][r] + bias;
                    int pk = __builtin_amdgcn_cvt_pk_fp8_f32(v, v, 0, false);
                    AB8[(size_t)node * 256 + j] = (u8)pk;
                }
            }
        }
    }
}

// ---------------- kernel 2: barrier-free wave-autonomous edge MLP + scatter ----------------
// r9: cross the 128-VGPR boundary. eml/cdl are no longer loop-carried (loaded
// per-tile, used only in scatter); __launch_bounds__(256,4) caps at 128 VGPR
// -> 4 waves/SIMD. r8 was 136 VGPR -> 2 waves/SIMD -> latency exposed.
__global__ __launch_bounds__(256, 4) void edge_kernel(
        const u8* __restrict__ AB8, const u16* __restrict__ W2T,
        const int* __restrict__ eidx, const float* __restrict__ coord_diff,
        const float* __restrict__ edge_attr, const float* __restrict__ edge_mask,
        const float* __restrict__ W1, const float* __restrict__ b2,
        const float* __restrict__ W3, float* __restrict__ agg, int E) {
    __shared__ u16 w2s[128 * 128];   // swizzled W2T copy (32 KB)
    __shared__ float ssc[4][16];     // per-wave scale scratch
    __shared__ float sw1c[128];      // W1 edge_attr row
    __shared__ float sb2[128];
    __shared__ float sw3[128];

    const int tid = threadIdx.x;
    const int lane = tid & 63;
    const int wv = tid >> 6;
    const int le = lane & 15;        // edge-sub (A rows) / col-sub (B cols)
    const int lg = lane >> 4;        // k-chunk group 0..3

    // stage W2T -> LDS, swizzled: byte ^= (row&7)<<4
    #pragma unroll
    for (int it = 0; it < 8; ++it) {
        int idx = it * 256 + tid;        // 2048 x 16B = 32 KB
        int j = idx >> 4, c16 = idx & 15;
        uint4 v = *(const uint4*)((const char*)W2T + idx * 16);
        *(uint4*)((char*)w2s + j * 256 + ((c16 * 16) ^ ((j & 7) << 4))) = v;
    }
    if (tid < 128) {
        sw1c[tid] = W1[256 * 128 + tid];
        sb2[tid]  = b2[tid];
        sw3[tid]  = W3[tid];
    }
    __syncthreads();                  // LDS tables ready (only barrier in kernel)

    const int ntiles = (E + 15) >> 4;
    const int wpb = blockDim.x >> 6;
    const int nwaves = gridDim.x * wpb;
    int tile = blockIdx.x * wpb + wv;
    if (tile >= ntiles) return;

    // ---- prologue: meta(t0) only (row/col/attr)
    int e0 = tile << 4;
    int epc = min(e0 + le, E - 1);
    int rowc = eidx[epc];
    int colc = eidx[E + epc];
    float eac = edge_attr[epc];

    while (true) {
        // issue gather(cur) -- consumed by convert below (TLP hides latency)
        uint2 va[4], vb[4];
        {
            const char* rp = (const char*)(AB8 + (size_t)rowc * 256);
            const char* cp = (const char*)(AB8 + (size_t)colc * 256 + 128);
            #pragma unroll
            for (int ks = 0; ks < 4; ++ks) {
                va[ks] = *(const uint2*)(rp + ks * 32 + lg * 8);
                vb[ks] = *(const uint2*)(cp + ks * 32 + lg * 8);
            }
        }
        // mask/coord_diff for THIS tile: needed only at scatter (end of body),
        // issued here so latency hides under convert + MFMA. Not loop-carried.
        float eml = edge_mask[min(e0 + le, E - 1)];
        float cdl = coord_diff[min(e0 * 3 + lane, E * 3 - 1)];

        // issue meta(next) -- latency hides under convert + MFMA
        int next = tile + nwaves;
        bool hn = next < ntiles;
        int ne0 = (hn ? next : tile) << 4;
        int nepc = min(ne0 + le, E - 1);
        int rown = eidx[nepc];
        int coln = eidx[E + nepc];
        float ean = edge_attr[nepc];

        // convert fp8 gathers -> bf16 A-fragments (layer-1 finish + silu)
        short8 pa[4];
        #pragma unroll
        for (int ks = 0; ks < 4; ++ks) {
            u32 a0 = va[ks].x, a1 = va[ks].y;
            u32 b0 = vb[ks].x, b1_ = vb[ks].y;
            f32x2 fa[4], fb[4];
            fa[0] = __builtin_amdgcn_cvt_pk_f32_fp8(a0, false);
            fa[1] = __builtin_amdgcn_cvt_pk_f32_fp8(a0, true);
            fa[2] = __builtin_amdgcn_cvt_pk_f32_fp8(a1, false);
            fa[3] = __builtin_amdgcn_cvt_pk_f32_fp8(a1, true);
            fb[0] = __builtin_amdgcn_cvt_pk_f32_fp8(b0, false);
            fb[1] = __builtin_amdgcn_cvt_pk_f32_fp8(b0, true);
            fb[2] = __builtin_amdgcn_cvt_pk_f32_fp8(b1_, false);
            fb[3] = __builtin_amdgcn_cvt_pk_f32_fp8(b1_, true);
            union { u32 w[4]; short8 s; } u;
            #pragma unroll
            for (int jp = 0; jp < 4; ++jp) {
                float2 wc = *(const float2*)&sw1c[ks * 32 + lg * 8 + 2 * jp];
                float p0 = fa[jp].x + fb[jp].x + eac * wc.x;
                float p1 = fa[jp].y + fb[jp].y + eac * wc.y;
                u.w[jp] = __builtin_amdgcn_perm(__float_as_uint(silu(p1)), __float_as_uint(silu(p0)), 0x07060302);
            }
            pa[ks] = u.s;
        }

        // layer 2 in two n-halves (acc[4] live instead of acc[8])
        float s[4] = { 0.f, 0.f, 0.f, 0.f };
        #pragma unroll
        for (int hf = 0; hf < 2; ++hf) {
            f32x4 acc[4] = {};
            #pragma unroll
            for (int ks = 0; ks < 4; ++ks) {
                #pragma unroll
                for (int nt = 0; nt < 4; ++nt) {
                    int row = (hf * 4 + nt) * 16 + le;
                    const short8 bwf = *(const short8*)((const char*)w2s +
                            row * 256 + (((ks * 64) + lg * 16) ^ ((le & 7) << 4)));
                    acc[nt] = __builtin_amdgcn_mfma_f32_16x16x32_bf16(pa[ks], bwf, acc[nt], 0, 0, 0);
                }
            }
            #pragma unroll
            for (int r = 0; r < 4; ++r) {
                #pragma unroll
                for (int nt = 0; nt < 4; ++nt) {
                    int j = (hf * 4 + nt) * 16 + le;
                    s[r] += silu(acc[nt][r] + sb2[j]) * sw3[j];
                }
            }
        }
        #pragma unroll
        for (int r = 0; r < 4; ++r) {
            float t = s[r];
            t += __shfl_xor(t, 1);
            t += __shfl_xor(t, 2);
            t += __shfl_xor(t, 4);
            t += __shfl_xor(t, 8);
            s[r] = t;                 // edge lg*4+r, valid at le==0
        }
        if (le == 0) {
            f32x4 sv = { s[0], s[1], s[2], s[3] };
            *(f32x4*)&ssc[wv][lg * 4] = sv;   // same-wave LDS, lgkmcnt-ordered
        }

        // scatter: 3 atomics per edge (lanes 0..47)
        int els = (lane < 48) ? (lane / 3) : 0;
        int rA = __shfl(rowc, els);
        float emA = __shfl(eml, els);
        float sc = ssc[wv][els];
        if (lane < 48 && (e0 + els) < E)
            atomicAdd(&agg[rA * 3 + (lane - els * 3)], cdl * emA * sc);

        if (!hn) break;
        tile = next; e0 = ne0;
        rowc = rown; colc = coln; eac = ean;
    }
}

// ---------------- kernel 3: coord update ----------------
__global__ void finalize(const float* __restrict__ coord, const float* __restrict__ agg,
                         const float* __restrict__ node_mask, float* __restrict__ out, int n3) {
    int i = blockIdx.x * blockDim.x + threadIdx.x;
    if (i < n3) {
        int n = i / 3;
        out[i] = (coord[i] + agg[i] * NORM_INV) * node_mask[n];
    }
}

extern "C" void kernel_launch(void* const* d_in, const int* in_sizes, int n_in,
                              void* d_out, int out_size, void* d_ws, size_t ws_size,
                              hipStream_t stream) {
    const float* h          = (const float*)d_in[0];
    const float* coord      = (const float*)d_in[1];
    const int*   eidx       = (const int*)d_in[2];
    const float* coord_diff = (const float*)d_in[3];
    const float* edge_attr  = (const float*)d_in[4];
    const float* node_mask  = (const float*)d_in[5];
    const float* edge_mask  = (const float*)d_in[6];
    const float* W1         = (const float*)d_in[7];
    const float* b1         = (const float*)d_in[8];
    const float* W2         = (const float*)d_in[9];
    const float* b2         = (const float*)d_in[10];
    const float* W3         = (const float*)d_in[11];

    int N = in_sizes[0] / 128;   // 50000
    int E = in_sizes[2] / 2;     // 800000

    char* ws = (char*)d_ws;
    size_t off = 0;
    u8*  AB8   = (u8*)(ws + off);  off += (size_t)N * 256; off = (off + 255) & ~(size_t)255;
    u16* W1abT = (u16*)(ws + off); off += 256 * 128 * sizeof(u16);
    u16* W2T   = (u16*)(ws + off); off += 128 * 128 * sizeof(u16);
    float* agg = (float*)(ws + off); off += (size_t)N * 3 * sizeof(float);

    hipMemsetAsync(agg, 0, (size_t)N * 3 * sizeof(float), stream);
    hipLaunchKernelGGL(prep_weights, dim3(192), dim3(256), 0, stream, W1, W2, W1abT, W2T);
    hipLaunchKernelGGL(ab_kernel, dim3((N + 31) / 32), dim3(256), 0, stream, h, b1, W1abT, AB8, N);
    hipLaunchKernelGGL(edge_kernel, dim3(4096), dim3(256), 0, stream,
                       AB8, W2T, eidx, coord_diff, edge_attr, edge_mask, W1, b2, W3, agg, E);
    int n3 = N * 3;
    hipLaunchKernelGGL(finalize, dim3((n3 + 255) / 256), dim3(256), 0, stream,
                       coord, agg, node_mask, (float*)d_out, n3);
}

// Round 10
// 171.375 us; speedup vs baseline: 2.6073x; 2.6073x over previous
//
#include <hip/hip_runtime.h>
#include <hip/hip_bf16.h>

typedef __attribute__((ext_vector_type(8))) short short8;
typedef __attribute__((ext_vector_type(4))) float f32x4;
typedef __attribute__((ext_vector_type(2))) float f32x2;
typedef unsigned short u16;
typedef unsigned int u32;
typedef unsigned char u8;
typedef unsigned long long u64;
typedef long long i64;

#define NORM_INV (1.0f / 100.0f)

__device__ __forceinline__ float silu(float x) {
    return x * __builtin_amdgcn_rcpf(1.0f + __expf(-x));
}

__device__ __forceinline__ u16 f2bf(float x) {
    union { float f; u32 u; } v; v.f = x;
    u32 r = v.u + 0x7fff + ((v.u >> 16) & 1);   // RNE
    return (u16)(r >> 16);
}

// ---------------- kernel 0: weight transposes (tiny) ----------------
__global__ void prep_weights(const float* __restrict__ W1, const float* __restrict__ W2,
                             u16* __restrict__ W1abT, u8* __restrict__ W2T8) {
    int idx = blockIdx.x * blockDim.x + threadIdx.x;
    if (idx < 256 * 128) {
        int j = idx >> 7, k = idx & 127;
        float v = (j < 128) ? W1[k * 128 + j] : W1[(128 + k) * 128 + (j - 128)];
        W1abT[j * 128 + k] = f2bf(v);
    } else if (idx < 256 * 128 + 128 * 128) {
        int t = idx - 256 * 128;
        int n = t >> 7, k = t & 127;
        float v = W2[k * 128 + n];
        int pk = __builtin_amdgcn_cvt_pk_fp8_f32(v, v, 0, false);
        W2T8[n * 128 + k] = (u8)pk;
    }
}

// ---------------- kernel 1: AB8[node][256] = fp8[h@W1a + b1 | h@W1b] ----------------
__global__ __launch_bounds__(256) void ab_kernel(const float* __restrict__ h,
        const float* __restrict__ b1, const u16* __restrict__ W1abT,
        u8* __restrict__ AB8, int N) {
    __shared__ u16 hs[32 * 128];     // 32 nodes x 128 k, bf16, XOR-swizzled
    int tid = threadIdx.x;
    int n0 = blockIdx.x * 32;
    int lane = tid & 63, wave = tid >> 6;

    #pragma unroll
    for (int it = 0; it < 8; ++it) {
        int item = it * 256 + tid;          // 2048 items, 2 k each
        int m = item >> 6;
        int k = (item & 63) * 2;
        float2 hv = make_float2(0.f, 0.f);
        if (n0 + m < N) hv = *(const float2*)(h + (size_t)(n0 + m) * 128 + k);
        u32 pk = (u32)f2bf(hv.x) | ((u32)f2bf(hv.y) << 16);
        int byteoff = m * 256 + ((k * 2) ^ ((m & 7) << 4));
        *(u32*)((char*)hs + byteoff) = pk;
    }

    short8 bw[4][4];
    #pragma unroll
    for (int nt = 0; nt < 4; ++nt) {
        int j = wave * 64 + nt * 16 + (lane & 15);
        #pragma unroll
        for (int ks = 0; ks < 4; ++ks)
            bw[nt][ks] = *(const short8*)((const char*)W1abT + j * 256 + ks * 64 + (lane >> 4) * 16);
    }
    __syncthreads();

    f32x4 acc[2][4] = {};
    #pragma unroll
    for (int ks = 0; ks < 4; ++ks) {
        short8 a[2];
        #pragma unroll
        for (int mt = 0; mt < 2; ++mt) {
            int row = mt * 16 + (lane & 15);
            int byteoff = row * 256 + (((ks * 64) + ((lane >> 4) * 16)) ^ ((row & 7) << 4));
            a[mt] = *(short8*)((char*)hs + byteoff);
        }
        #pragma unroll
        for (int mt = 0; mt < 2; ++mt)
            #pragma unroll
            for (int nt = 0; nt < 4; ++nt)
                acc[mt][nt] = __builtin_amdgcn_mfma_f32_16x16x32_bf16(a[mt], bw[nt][ks], acc[mt][nt], 0, 0, 0);
    }

    // epilogue: + b1 on A-half, store fp8 e4m3
    #pragma unroll
    for (int mt = 0; mt < 2; ++mt) {
        #pragma unroll
        for (int nt = 0; nt < 4; ++nt) {
            int j = wave * 64 + nt * 16 + (lane & 15);
            float bias = (j < 128) ? b1[j] : 0.f;
            #pragma unroll
            for (int r = 0; r < 4; ++r) {
                int node = n0 + mt * 16 + (lane >> 4) * 4 + r;
                if (node < N) {
                    float v = acc[mt][nt][r] + bias;
                    int pk = __builtin_amdgcn_cvt_pk_fp8_f32(v, v, 0, false);
                    AB8[(size_t)node * 256 + j] = (u8)pk;
                }
            }
        }
    }
}

// ---------------- kernel 2: barrier-free wave-autonomous edge MLP + scatter ----------------
// r10: (a) volatile LDS-table reads (compiler was hoisting loop-invariant LDS
// loads into registers -> 136+ VGPR); (b) fp8 layer-2 MFMA: pa 16->8 regs,
// w2s 32->16 KB so LDS no longer caps blocks/CU at 4. No launch_bounds
// occupancy forcing (r5/r9: it collapses the allocator to 64 VGPR + spills).
__global__ __launch_bounds__(256) void edge_kernel(
        const u8* __restrict__ AB8, const u8* __restrict__ W2T8,
        const int* __restrict__ eidx, const float* __restrict__ coord_diff,
        const float* __restrict__ edge_attr, const float* __restrict__ edge_mask,
        const float* __restrict__ W1, const float* __restrict__ b2,
        const float* __restrict__ W3, float* __restrict__ agg, int E) {
    __shared__ u8 w2s8[128 * 128];   // swizzled fp8 W2T copy (16 KB)
    __shared__ float ssc[4][16];     // per-wave scale scratch
    __shared__ float sw1c[128];      // W1 edge_attr row
    __shared__ float sb2[128];
    __shared__ float sw3[128];

    const int tid = threadIdx.x;
    const int lane = tid & 63;
    const int wv = tid >> 6;
    const int le = lane & 15;        // edge-sub (A rows) / col-sub (B cols)
    const int lg = lane >> 4;        // k-chunk group 0..3

    // stage W2T8 -> LDS in 8B granules, swizzle: byte ^= (row&7)<<4
    #pragma unroll
    for (int it = 0; it < 8; ++it) {
        int idx = it * 256 + tid;        // 2048 x 8B = 16 KB
        int row = idx >> 4, c8 = idx & 15;
        u64 v = *(const u64*)(W2T8 + row * 128 + c8 * 8);
        *(u64*)(w2s8 + row * 128 + ((c8 * 8) ^ ((row & 7) << 4))) = v;
    }
    if (tid < 128) {
        sw1c[tid] = W1[256 * 128 + tid];
        sb2[tid]  = b2[tid];
        sw3[tid]  = W3[tid];
    }
    __syncthreads();                  // LDS tables ready (only barrier in kernel)

    volatile const float* vw1c = sw1c;   // volatile: forbid loop-invariant hoist
    volatile const float* vb2  = sb2;
    volatile const float* vw3  = sw3;

    const int ntiles = (E + 15) >> 4;
    const int wpb = blockDim.x >> 6;
    const int nwaves = gridDim.x * wpb;
    int tile = blockIdx.x * wpb + wv;
    if (tile >= ntiles) return;

    // ---- prologue: meta(t0) only (row/col/attr)
    int e0 = tile << 4;
    int epc = min(e0 + le, E - 1);
    int rowc = eidx[epc];
    int colc = eidx[E + epc];
    float eac = edge_attr[epc];

    while (true) {
        // issue gather(cur) -- consumed by convert below (TLP hides latency)
        uint2 va[4], vb[4];
        {
            const char* rp = (const char*)(AB8 + (size_t)rowc * 256);
            const char* cp = (const char*)(AB8 + (size_t)colc * 256 + 128);
            #pragma unroll
            for (int ks = 0; ks < 4; ++ks) {
                va[ks] = *(const uint2*)(rp + ks * 32 + lg * 8);
                vb[ks] = *(const uint2*)(cp + ks * 32 + lg * 8);
            }
        }
        // mask/coord_diff for THIS tile (used only at scatter; latency hides)
        float eml = edge_mask[min(e0 + le, E - 1)];
        float cdl = coord_diff[min(e0 * 3 + lane, E * 3 - 1)];

        // issue meta(next)
        int next = tile + nwaves;
        bool hn = next < ntiles;
        int ne0 = (hn ? next : tile) << 4;
        int nepc = min(ne0 + le, E - 1);
        int rown = eidx[nepc];
        int coln = eidx[E + nepc];
        float ean = edge_attr[nepc];

        // convert fp8 gathers -> fp8 A-fragments (layer-1 finish + silu)
        i64 pa[4];
        #pragma unroll
        for (int ks = 0; ks < 4; ++ks) {
            u32 a0 = va[ks].x, a1 = va[ks].y;
            u32 b0 = vb[ks].x, b1_ = vb[ks].y;
            f32x2 fa[4], fb[4];
            fa[0] = __builtin_amdgcn_cvt_pk_f32_fp8(a0, false);
            fa[1] = __builtin_amdgcn_cvt_pk_f32_fp8(a0, true);
            fa[2] = __builtin_amdgcn_cvt_pk_f32_fp8(a1, false);
            fa[3] = __builtin_amdgcn_cvt_pk_f32_fp8(a1, true);
            fb[0] = __builtin_amdgcn_cvt_pk_f32_fp8(b0, false);
            fb[1] = __builtin_amdgcn_cvt_pk_f32_fp8(b0, true);
            fb[2] = __builtin_amdgcn_cvt_pk_f32_fp8(b1_, false);
            fb[3] = __builtin_amdgcn_cvt_pk_f32_fp8(b1_, true);
            float x[8];
            #pragma unroll
            for (int jp = 0; jp < 4; ++jp) {
                float wcx = vw1c[ks * 32 + lg * 8 + 2 * jp];
                float wcy = vw1c[ks * 32 + lg * 8 + 2 * jp + 1];
                x[2 * jp]     = silu(fa[jp].x + fb[jp].x + eac * wcx);
                x[2 * jp + 1] = silu(fa[jp].y + fb[jp].y + eac * wcy);
            }
            u32 lo = 0, hi = 0;
            lo = __builtin_amdgcn_cvt_pk_fp8_f32(x[0], x[1], lo, false);
            lo = __builtin_amdgcn_cvt_pk_fp8_f32(x[2], x[3], lo, true);
            hi = __builtin_amdgcn_cvt_pk_fp8_f32(x[4], x[5], hi, false);
            hi = __builtin_amdgcn_cvt_pk_fp8_f32(x[6], x[7], hi, true);
            union { uint2 u; i64 l; } c; c.u = make_uint2(lo, hi);
            pa[ks] = c.l;
        }

        // layer 2: fp8 MFMA in two n-halves (acc[4] live, not acc[8])
        float s[4] = { 0.f, 0.f, 0.f, 0.f };
        #pragma unroll
        for (int hf = 0; hf < 2; ++hf) {
            f32x4 acc[4] = {};
            #pragma unroll
            for (int ks = 0; ks < 4; ++ks) {
                #pragma unroll
                for (int nt = 0; nt < 4; ++nt) {
                    int row = (hf * 4 + nt) * 16 + le;
                    u64 b8 = *(const u64*)(w2s8 + row * 128 +
                             (((ks * 32) + (lg * 8)) ^ ((le & 7) << 4)));
                    acc[nt] = __builtin_amdgcn_mfma_f32_16x16x32_fp8_fp8(pa[ks], (i64)b8, acc[nt], 0, 0, 0);
                }
            }
            #pragma unroll
            for (int nt = 0; nt < 4; ++nt) {
                int j = (hf * 4 + nt) * 16 + le;
                float b2j = vb2[j];
                float w3j = vw3[j];
                #pragma unroll
                for (int r = 0; r < 4; ++r)
                    s[r] += silu(acc[nt][r] + b2j) * w3j;
            }
        }
        #pragma unroll
        for (int r = 0; r < 4; ++r) {
            float t = s[r];
            t += __shfl_xor(t, 1);
            t += __shfl_xor(t, 2);
            t += __shfl_xor(t, 4);
            t += __shfl_xor(t, 8);
            s[r] = t;                 // edge lg*4+r, valid at le==0
        }
        if (le == 0) {
            f32x4 sv = { s[0], s[1], s[2], s[3] };
            *(f32x4*)&ssc[wv][lg * 4] = sv;   // same-wave LDS, lgkmcnt-ordered
        }

        // scatter: 3 atomics per edge (lanes 0..47)
        int els = (lane < 48) ? (lane / 3) : 0;
        int rA = __shfl(rowc, els);
        float emA = __shfl(eml, els);
        float sc = ssc[wv][els];
        if (lane < 48 && (e0 + els) < E)
            atomicAdd(&agg[rA * 3 + (lane - els * 3)], cdl * emA * sc);

        if (!hn) break;
        tile = next; e0 = ne0;
        rowc = rown; colc = coln; eac = ean;
    }
}

// ---------------- kernel 3: coord update ----------------
__global__ void finalize(const float* __restrict__ coord, const float* __restrict__ agg,
                         const float* __restrict__ node_mask, float* __restrict__ out, int n3) {
    int i = blockIdx.x * blockDim.x + threadIdx.x;
    if (i < n3) {
        int n = i / 3;
        out[i] = (coord[i] + agg[i] * NORM_INV) * node_mask[n];
    }
}

extern "C" void kernel_launch(void* const* d_in, const int* in_sizes, int n_in,
                              void* d_out, int out_size, void* d_ws, size_t ws_size,
                              hipStream_t stream) {
    const float* h          = (const float*)d_in[0];
    const float* coord      = (const float*)d_in[1];
    const int*   eidx       = (const int*)d_in[2];
    const float* coord_diff = (const float*)d_in[3];
    const float* edge_attr  = (const float*)d_in[4];
    const float* node_mask  = (const float*)d_in[5];
    const float* edge_mask  = (const float*)d_in[6];
    const float* W1         = (const float*)d_in[7];
    const float* b1         = (const float*)d_in[8];
    const float* W2         = (const float*)d_in[9];
    const float* b2         = (const float*)d_in[10];
    const float* W3         = (const float*)d_in[11];

    int N = in_sizes[0] / 128;   // 50000
    int E = in_sizes[2] / 2;     // 800000

    char* ws = (char*)d_ws;
    size_t off = 0;
    u8*  AB8   = (u8*)(ws + off);  off += (size_t)N * 256; off = (off + 255) & ~(size_t)255;
    u16* W1abT = (u16*)(ws + off); off += 256 * 128 * sizeof(u16);
    u8*  W2T8  = (u8*)(ws + off);  off += 128 * 128; off = (off + 255) & ~(size_t)255;
    float* agg = (float*)(ws + off); off += (size_t)N * 3 * sizeof(float);

    hipMemsetAsync(agg, 0, (size_t)N * 3 * sizeof(float), stream);
    hipLaunchKernelGGL(prep_weights, dim3(192), dim3(256), 0, stream, W1, W2, W1abT, W2T8);
    hipLaunchKernelGGL(ab_kernel, dim3((N + 31) / 32), dim3(256), 0, stream, h, b1, W1abT, AB8, N);
    hipLaunchKernelGGL(edge_kernel, dim3(2048), dim3(256), 0, stream,
                       AB8, W2T8, eidx, coord_diff, edge_attr, edge_mask, W1, b2, W3, agg, E);
    int n3 = N * 3;
    hipLaunchKernelGGL(finalize, dim3((n3 + 255) / 256), dim3(256), 0, stream,
                       coord, agg, node_mask, (float*)d_out, n3);
}